// Round 1
// baseline (69.504 us; speedup 1.0000x reference)
//
#include <hip/hip_runtime.h>
#include <math.h>

// Problem constants
#define BB 4
#define NN 8192
#define KK 16
#define DD 128
#define GG 32
#define NPTS (BB * NN)          // 32768
#define GATHER_BLOCKS 2048      // each handles 16 points
#define BN_EPS 1e-5f

// ---------------------------------------------------------------------------
// Kernel 0: transpose proj_w [D,D] -> wt[c][d] = w[d][c]
// ---------------------------------------------------------------------------
__global__ void transpose_w(const float* __restrict__ w, float* __restrict__ wt) {
    int i = blockIdx.x * 256 + threadIdx.x;   // 16384 elements
    int d = i >> 7;
    int c = i & 127;
    wt[c * 128 + d] = w[d * 128 + c];
}

// ---------------------------------------------------------------------------
// Kernel 1: h[p][d] = sum_c x[p][c] * wt[c][d]      (p = 0..NPTS)
// Block: 256 threads, tile 64 rows x 128 cols, thread tile 8x4.
// ---------------------------------------------------------------------------
__global__ __launch_bounds__(256) void gemm_h(const float* __restrict__ x,
                                              const float* __restrict__ wt,
                                              float* __restrict__ h) {
    __shared__ float xs[64][128];
    const int block_row = blockIdx.x * 64;
    const int t = threadIdx.x;

    // stage 64x128 x-tile: 2048 float4, 8 per thread
    const float4* xg = reinterpret_cast<const float4*>(x + (size_t)block_row * 128);
    float4* xs4 = reinterpret_cast<float4*>(&xs[0][0]);
#pragma unroll
    for (int i = 0; i < 8; ++i) xs4[t + 256 * i] = xg[t + 256 * i];
    __syncthreads();

    const int ty = t >> 5;          // 0..7
    const int tx = t & 31;          // 0..31
    const int r0 = ty * 8;
    const int c0 = tx * 4;

    float acc[8][4];
#pragma unroll
    for (int r = 0; r < 8; ++r)
#pragma unroll
        for (int j = 0; j < 4; ++j) acc[r][j] = 0.f;

    for (int c4 = 0; c4 < 32; ++c4) {
        float4 wv[4];
#pragma unroll
        for (int j = 0; j < 4; ++j)
            wv[j] = *reinterpret_cast<const float4*>(wt + (size_t)(c4 * 4 + j) * 128 + c0);
#pragma unroll
        for (int r = 0; r < 8; ++r) {
            float4 xv = *reinterpret_cast<const float4*>(&xs[r0 + r][c4 * 4]);
            const float xc[4] = {xv.x, xv.y, xv.z, xv.w};
#pragma unroll
            for (int j = 0; j < 4; ++j) {
                acc[r][0] = fmaf(xc[j], wv[j].x, acc[r][0]);
                acc[r][1] = fmaf(xc[j], wv[j].y, acc[r][1]);
                acc[r][2] = fmaf(xc[j], wv[j].z, acc[r][2]);
                acc[r][3] = fmaf(xc[j], wv[j].w, acc[r][3]);
            }
        }
    }

#pragma unroll
    for (int r = 0; r < 8; ++r) {
        float4 o = make_float4(acc[r][0], acc[r][1], acc[r][2], acc[r][3]);
        *reinterpret_cast<float4*>(h + (size_t)(block_row + r0 + r) * 128 + c0) = o;
    }
}

// ---------------------------------------------------------------------------
// Kernel 2: gather h at knn, add spatial encoding, max over K.
// Writes agg into out (d_out) and per-block BN partial sums.
// Block: 256 threads = 8 points x 32 groups; 2 iterations -> 16 points/block.
// partials layout: psum[ch][block] at [ch*GATHER_BLOCKS + blk],
//                  psumsq at offset 128*GATHER_BLOCKS.
// ---------------------------------------------------------------------------
__global__ __launch_bounds__(256) void gather_max(const float* __restrict__ h,
                                                  const float* __restrict__ xyz,
                                                  const int* __restrict__ knn,
                                                  const float* __restrict__ coor,
                                                  const float* __restrict__ scale,
                                                  float* __restrict__ out,
                                                  float* __restrict__ partials) {
    const int t = threadIdx.x;
    const int g = t & 31;    // group id (channels 4g..4g+3)
    const int sub = t >> 5;  // point slot 0..7

    const float c0w = coor[g * 3 + 0];
    const float c1w = coor[g * 3 + 1];
    const float c2w = coor[g * 3 + 2];
    const float sg = scale[g];
    const float s2 = sg * sg;

    float lsum[4] = {0.f, 0.f, 0.f, 0.f};
    float lsq[4]  = {0.f, 0.f, 0.f, 0.f};

#pragma unroll
    for (int it = 0; it < 2; ++it) {
        const int p = blockIdx.x * 16 + it * 8 + sub;   // 0..32767
        const int b = p >> 13;                          // / NN
        const float* ctr = xyz + (size_t)p * 3;
        const float cx = ctr[0], cy = ctr[1], cz = ctr[2];
        const int* kn = knn + (size_t)p * KK;

        float4 acc = make_float4(-INFINITY, -INFINITY, -INFINITY, -INFINITY);

#pragma unroll
        for (int k = 0; k < KK; ++k) {
            const int idx = kn[k];
            const int row = b * NN + idx;
            const float* nb = xyz + (size_t)row * 3;
            const float rx = nb[0] - cx;
            const float ry = nb[1] - cy;
            const float rz = nb[2] - cz;
            const float r2 = rx * rx + ry * ry + rz * rz;
            const float e = rx * c0w + ry * c1w + rz * c2w + r2 * s2;
            const float4 hv = *reinterpret_cast<const float4*>(h + (size_t)row * 128 + g * 4);
            acc.x = fmaxf(acc.x, hv.x + e);
            acc.y = fmaxf(acc.y, hv.y + e);
            acc.z = fmaxf(acc.z, hv.z + e);
            acc.w = fmaxf(acc.w, hv.w + e);
        }

        *reinterpret_cast<float4*>(out + (size_t)p * 128 + g * 4) = acc;

        lsum[0] += acc.x; lsum[1] += acc.y; lsum[2] += acc.z; lsum[3] += acc.w;
        lsq[0] += acc.x * acc.x; lsq[1] += acc.y * acc.y;
        lsq[2] += acc.z * acc.z; lsq[3] += acc.w * acc.w;
    }

    // block reduction across the 8 point-slots
    __shared__ float red[8][128];
#pragma unroll
    for (int j = 0; j < 4; ++j) red[sub][g * 4 + j] = lsum[j];
    __syncthreads();
    if (t < 128) {
        float s = 0.f;
#pragma unroll
        for (int s8 = 0; s8 < 8; ++s8) s += red[s8][t];
        partials[(size_t)t * GATHER_BLOCKS + blockIdx.x] = s;
    }
    __syncthreads();
#pragma unroll
    for (int j = 0; j < 4; ++j) red[sub][g * 4 + j] = lsq[j];
    __syncthreads();
    if (t < 128) {
        float q = 0.f;
#pragma unroll
        for (int s8 = 0; s8 < 8; ++s8) q += red[s8][t];
        partials[(size_t)(128 + t) * GATHER_BLOCKS + blockIdx.x] = q;
    }
}

// ---------------------------------------------------------------------------
// Kernel 3: per-channel stats -> stats[ch] = rstd*bnw, stats[128+ch] = bnb - mean*rstd*bnw
// Grid: 128 blocks (one per channel), 256 threads.
// ---------------------------------------------------------------------------
__global__ __launch_bounds__(256) void bn_stats(const float* __restrict__ partials,
                                                const float* __restrict__ bnw,
                                                const float* __restrict__ bnb,
                                                float* __restrict__ stats) {
    const int ch = blockIdx.x;
    const int t = threadIdx.x;
    const float* ps = partials + (size_t)ch * GATHER_BLOCKS;
    const float* pq = partials + (size_t)(128 + ch) * GATHER_BLOCKS;
    float s = 0.f, q = 0.f;
    for (int i = t; i < GATHER_BLOCKS; i += 256) { s += ps[i]; q += pq[i]; }
    __shared__ float rs[256], rq[256];
    rs[t] = s; rq[t] = q;
    __syncthreads();
    for (int off = 128; off > 0; off >>= 1) {
        if (t < off) { rs[t] += rs[t + off]; rq[t] += rq[t + off]; }
        __syncthreads();
    }
    if (t == 0) {
        const float inv_n = 1.0f / (float)NPTS;
        const float mean = rs[0] * inv_n;
        const float var = rq[0] * inv_n - mean * mean;
        const float rstd = rsqrtf(var + BN_EPS);
        const float A = rstd * bnw[ch];
        stats[ch] = A;
        stats[128 + ch] = bnb[ch] - mean * A;
    }
}

// ---------------------------------------------------------------------------
// Kernel 4: in-place normalize d_out: y = v*A[ch] + C[ch]
// ---------------------------------------------------------------------------
__global__ __launch_bounds__(256) void bn_apply(float* __restrict__ out,
                                                const float* __restrict__ stats) {
    const int i = blockIdx.x * 256 + threadIdx.x;   // float4 index, 1M total
    const int ch4 = i & 31;                         // float4 slot within a row
    float4 v = reinterpret_cast<float4*>(out)[i];
    const float4 A = reinterpret_cast<const float4*>(stats)[ch4];
    const float4 C = reinterpret_cast<const float4*>(stats + 128)[ch4];
    v.x = fmaf(v.x, A.x, C.x);
    v.y = fmaf(v.y, A.y, C.y);
    v.z = fmaf(v.z, A.z, C.z);
    v.w = fmaf(v.w, A.w, C.w);
    reinterpret_cast<float4*>(out)[i] = v;
}

// ---------------------------------------------------------------------------
extern "C" void kernel_launch(void* const* d_in, const int* in_sizes, int n_in,
                              void* d_out, int out_size, void* d_ws, size_t ws_size,
                              hipStream_t stream) {
    const float* x      = (const float*)d_in[0];
    const float* xyz    = (const float*)d_in[1];
    const int*   knn    = (const int*)d_in[2];
    const float* proj_w = (const float*)d_in[3];
    const float* coor   = (const float*)d_in[4];
    const float* scale  = (const float*)d_in[5];
    const float* bnw    = (const float*)d_in[6];
    const float* bnb    = (const float*)d_in[7];
    float* out = (float*)d_out;

    char* ws = (char*)d_ws;
    float* h        = (float*)(ws);                               // 16 MB
    float* wt       = (float*)(ws + (size_t)NPTS * DD * 4);       // 64 KB
    float* partials = (float*)(ws + (size_t)NPTS * DD * 4 + 65536);       // 2 MB
    float* stats    = (float*)(ws + (size_t)NPTS * DD * 4 + 65536
                               + (size_t)2 * 128 * GATHER_BLOCKS * 4);    // 1 KB

    transpose_w<<<64, 256, 0, stream>>>(proj_w, wt);
    gemm_h<<<NPTS / 64, 256, 0, stream>>>(x, wt, h);
    gather_max<<<GATHER_BLOCKS, 256, 0, stream>>>(h, xyz, knn, coor, scale, out, partials);
    bn_stats<<<128, 256, 0, stream>>>(partials, bnw, bnb, stats);
    bn_apply<<<(NPTS * DD / 4) / 256, 256, 0, stream>>>(out, stats);
}